// Round 3
// baseline (375.692 us; speedup 1.0000x reference)
//
#include <hip/hip_runtime.h>
#include <hip/hip_bf16.h>
#include <stdint.h>

typedef unsigned short u16;
typedef __bf16 bf16x8 __attribute__((ext_vector_type(8)));
typedef float f32x4 __attribute__((ext_vector_type(4)));

#define D_DIM 1024
#define B_ROWS 16384
#define M_ROWS 32768          // 2*B
#define NOUT 1024             // per-GEMM output cols
#define BM 128
#define BN 128
#define BK 32

// ---------- bf16 bit helpers ----------
__device__ __forceinline__ u16 f2bs(float f) {
    union { float f; unsigned u; } v; v.f = f;
    unsigned r = v.u + 0x7FFFu + ((v.u >> 16) & 1u);   // RNE
    return (u16)(r >> 16);
}
__device__ __forceinline__ float bs2f(unsigned bits16) {
    union { unsigned u; float f; } v; v.u = bits16 << 16;
    return v.f;
}
__device__ __forceinline__ float bidx(uint2 v, int e) {
    unsigned w = (e < 2) ? v.x : v.y;
    unsigned sh = (unsigned)(e & 1) * 16u;
    return bs2f((w >> sh) & 0xFFFFu);
}
__device__ __forceinline__ uint2 pack4(float4 f) {
    uint2 r;
    r.x = (unsigned)f2bs(f.x) | ((unsigned)f2bs(f.y) << 16);
    r.y = (unsigned)f2bs(f.z) | ((unsigned)f2bs(f.w) << 16);
    return r;
}

#define GLD16(gsrc, ldst)                                                      \
    __builtin_amdgcn_global_load_lds(                                          \
        (const __attribute__((address_space(1))) void*)(gsrc),                 \
        (__attribute__((address_space(3))) void*)(ldst), 16, 0, 0)

// ---------- pass 1a: feats fp32 -> bf16, interleaved rows (2b, 2b+1) ----------
__global__ __launch_bounds__(256) void cvt_feats(const float* __restrict__ f1,
                                                 const float* __restrict__ f2,
                                                 u16* __restrict__ X) {
    size_t i4   = (size_t)blockIdx.x * 256 + threadIdx.x;   // one float4 per thread
    size_t base = i4 * 4;                                   // element idx in [B,D]
    size_t brow = base >> 10;                               // /1024
    size_t col  = base & 1023;
    float4 a = *(const float4*)(f1 + base);
    float4 b = *(const float4*)(f2 + base);
    *(uint2*)(X + (2 * brow) * D_DIM + col)     = pack4(a);
    *(uint2*)(X + (2 * brow + 1) * D_DIM + col) = pack4(b);
}

// ---------- pass 1b: weights fp32 -> bf16 concat [3072][1024], bias concat ----------
__global__ __launch_bounds__(256) void cvt_w(const float* __restrict__ Wq,
                                             const float* __restrict__ Wk,
                                             const float* __restrict__ Wv,
                                             const float* __restrict__ bq,
                                             const float* __restrict__ bk,
                                             const float* __restrict__ bv,
                                             u16* __restrict__ Wc,
                                             float* __restrict__ bc) {
    size_t i4   = (size_t)blockIdx.x * 256 + threadIdx.x;
    size_t base = i4 * 4;
    float4 q = *(const float4*)(Wq + base);
    float4 k = *(const float4*)(Wk + base);
    float4 v = *(const float4*)(Wv + base);
    *(uint2*)(Wc + base)                             = pack4(q);
    *(uint2*)(Wc + (size_t)D_DIM * D_DIM + base)     = pack4(k);
    *(uint2*)(Wc + (size_t)2 * D_DIM * D_DIM + base) = pack4(v);
    if (i4 < D_DIM / 4) {
        ((float4*)bc)[i4]                 = ((const float4*)bq)[i4];
        ((float4*)(bc + D_DIM))[i4]       = ((const float4*)bk)[i4];
        ((float4*)(bc + 2 * D_DIM))[i4]   = ((const float4*)bv)[i4];
    }
}

// ---------- pass 2: C[M,1024] = X[M,1024] @ W[1024,1024]^T + bias (bf16 out) ----------
__global__ __launch_bounds__(256) void gemm1024(const u16* __restrict__ X,
                                                const u16* __restrict__ W,
                                                const float* __restrict__ bias,
                                                u16* __restrict__ C) {
    constexpr int K = D_DIM;
    __shared__ u16 As[BM * BK];   // 8 KB
    __shared__ u16 Bs[BN * BK];   // 8 KB

    const int nTn = NOUT / BN;    // 8
    int bid = blockIdx.x;
    int tm = bid / nTn, tn = bid % nTn;
    const int m0 = tm * BM, n0 = tn * BN;

    const int tid  = threadIdx.x;
    const int lane = tid & 63;
    const int wave = tid >> 6;
    const int wr = wave >> 1, wc = wave & 1;    // 2x2 waves -> 64x64 each

    const int lr = lane & 15;
    const int lk = (lane >> 4) * 8;

    f32x4 acc[4][4] = {};

    // staging: thread covers 8 bf16 (16B); rows 0..63 in load 0, 64..127 in load 1
    const int r0 = tid >> 2;            // 0..63
    const int c0 = (tid & 3) * 8;
    const u16* aSrc0 = X + (size_t)(m0 + r0) * K + c0;
    const u16* aSrc1 = X + (size_t)(m0 + 64 + r0) * K + c0;
    const u16* bSrc0 = W + (size_t)(n0 + r0) * K + c0;
    const u16* bSrc1 = W + (size_t)(n0 + 64 + r0) * K + c0;
    u16* aDst0 = As + (size_t)tid * 8;
    u16* aDst1 = As + 2048 + (size_t)tid * 8;
    u16* bDst0 = Bs + (size_t)tid * 8;
    u16* bDst1 = Bs + 2048 + (size_t)tid * 8;

    for (int kt = 0; kt < K; kt += BK) {
        GLD16(aSrc0 + kt, aDst0);
        GLD16(aSrc1 + kt, aDst1);
        GLD16(bSrc0 + kt, bDst0);
        GLD16(bSrc1 + kt, bDst1);
        __syncthreads();

        bf16x8 af[4], bfr[4];
#pragma unroll
        for (int mf = 0; mf < 4; ++mf)
            af[mf] = *(const bf16x8*)(As + (wr * 64 + mf * 16 + lr) * BK + lk);
#pragma unroll
        for (int nf = 0; nf < 4; ++nf)
            bfr[nf] = *(const bf16x8*)(Bs + (wc * 64 + nf * 16 + lr) * BK + lk);
#pragma unroll
        for (int mf = 0; mf < 4; ++mf)
#pragma unroll
            for (int nf = 0; nf < 4; ++nf)
                acc[mf][nf] = __builtin_amdgcn_mfma_f32_16x16x32_bf16(
                    af[mf], bfr[nf], acc[mf][nf], 0, 0, 0);
        __syncthreads();
    }

    // epilogue: C/D layout col=lane&15, row=(lane>>4)*4+j  [verified m89]
    const int cr = (lane >> 4) * 4;
    const int cc = lane & 15;
#pragma unroll
    for (int mf = 0; mf < 4; ++mf) {
#pragma unroll
        for (int nf = 0; nf < 4; ++nf) {
            int col = n0 + wc * 64 + nf * 16 + cc;
            float bsv = bias[col];
#pragma unroll
            for (int j = 0; j < 4; ++j) {
                int row = m0 + wr * 64 + mf * 16 + cr + j;
                C[(size_t)row * NOUT + col] = f2bs(acc[mf][nf][j] + bsv);
            }
        }
    }
}

// ---------- pass 3: per-pair 2x2 attention -> combine weights (w0,w1) ----------
__global__ __launch_bounds__(256) void scores_k(const u16* __restrict__ Q,
                                                const u16* __restrict__ K,
                                                float2* __restrict__ wts) {
    const int wave = threadIdx.x >> 6;
    const int lane = threadIdx.x & 63;
    const size_t b = (size_t)blockIdx.x * 4 + wave;
    const u16* q0p = Q + (2 * b) * D_DIM;
    const u16* q1p = q0p + D_DIM;
    const u16* k0p = K + (2 * b) * D_DIM;
    const u16* k1p = k0p + D_DIM;

    float s00 = 0.f, s01 = 0.f, s10 = 0.f, s11 = 0.f;
#pragma unroll
    for (int s = 0; s < 4; ++s) {
        int c = s * 256 + lane * 4;
        uint2 q0 = *(const uint2*)(q0p + c);
        uint2 q1 = *(const uint2*)(q1p + c);
        uint2 k0 = *(const uint2*)(k0p + c);
        uint2 k1 = *(const uint2*)(k1p + c);
#pragma unroll
        for (int e = 0; e < 4; ++e) {
            float a0 = bidx(q0, e), a1 = bidx(q1, e);
            float c0 = bidx(k0, e), c1 = bidx(k1, e);
            s00 = fmaf(a0, c0, s00); s01 = fmaf(a0, c1, s01);
            s10 = fmaf(a1, c0, s10); s11 = fmaf(a1, c1, s11);
        }
    }
#pragma unroll
    for (int off = 32; off; off >>= 1) {
        s00 += __shfl_xor(s00, off);
        s01 += __shfl_xor(s01, off);
        s10 += __shfl_xor(s10, off);
        s11 += __shfl_xor(s11, off);
    }
    if (lane == 0) {
        const float sc = 1.0f / 32.0f;   // 1/sqrt(1024)
        s00 *= sc; s01 *= sc; s10 *= sc; s11 *= sc;
        float mA = fmaxf(s00, s01);
        float e00 = expf(s00 - mA), e01 = expf(s01 - mA);
        float rA = 1.0f / (e00 + e01);
        float mB = fmaxf(s10, s11);
        float e10 = expf(s10 - mB), e11 = expf(s11 - mB);
        float rB = 1.0f / (e10 + e11);
        float2 w;
        w.x = e00 * rA + e10 * rB;   // weight on V[s=0]
        w.y = e01 * rA + e11 * rB;   // weight on V[s=1]
        wts[b] = w;
    }
}

// ---------- pass 4: out[b] = w0*V[2b] + w1*V[2b+1] ----------
__global__ __launch_bounds__(256) void combine_k(const u16* __restrict__ V,
                                                 const float2* __restrict__ wts,
                                                 float* __restrict__ out) {
    size_t i4   = (size_t)blockIdx.x * 256 + threadIdx.x;
    size_t base = i4 * 4;
    size_t b    = base >> 10;
    size_t c    = base & 1023;
    float2 w = wts[b];
    uint2 v0 = *(const uint2*)(V + (2 * b) * D_DIM + c);
    uint2 v1 = *(const uint2*)(V + (2 * b + 1) * D_DIM + c);
    float4 o;
    o.x = w.x * bidx(v0, 0) + w.y * bidx(v1, 0);
    o.y = w.x * bidx(v0, 1) + w.y * bidx(v1, 1);
    o.z = w.x * bidx(v0, 2) + w.y * bidx(v1, 2);
    o.w = w.x * bidx(v0, 3) + w.y * bidx(v1, 3);
    *(float4*)(out + b * D_DIM + c) = o;
}

extern "C" void kernel_launch(void* const* d_in, const int* in_sizes, int n_in,
                              void* d_out, int out_size, void* d_ws, size_t ws_size,
                              hipStream_t stream) {
    const float* f1 = (const float*)d_in[0];
    const float* f2 = (const float*)d_in[1];
    const float* Wq = (const float*)d_in[2];
    const float* bq = (const float*)d_in[3];
    const float* Wk = (const float*)d_in[4];
    const float* bk = (const float*)d_in[5];
    const float* Wv = (const float*)d_in[6];
    const float* bv = (const float*)d_in[7];
    float* out = (float*)d_out;

    // workspace layout (≈198 MB total)
    char*   w   = (char*)d_ws;
    u16*    X   = (u16*)w;                                   // [32768,1024] bf16 (64 MB)
    u16*    Wc  = X + (size_t)M_ROWS * D_DIM;                // [3072,1024] bf16 (6 MB)
    float*  bc  = (float*)(Wc + (size_t)3 * D_DIM * D_DIM);  // [3072] f32
    float2* wts = (float2*)(bc + 3 * D_DIM);                 // [16384] f32x2 (128 KB)
    u16*    Kb  = (u16*)(wts + B_ROWS);                      // [32768,1024] bf16 (64 MB)
    u16*    Qb  = Kb + (size_t)M_ROWS * D_DIM;               // [32768,1024] bf16 (64 MB; reused for V)

    cvt_feats<<<(B_ROWS * D_DIM / 4) / 256, 256, 0, stream>>>(f1, f2, X);
    cvt_w<<<(D_DIM * D_DIM / 4) / 256, 256, 0, stream>>>(Wq, Wk, Wv, bq, bk, bv, Wc, bc);

    const int gemm_grid = (M_ROWS / BM) * (NOUT / BN);       // 2048
    gemm1024<<<gemm_grid, 256, 0, stream>>>(X, Wc, bc, Qb);                                     // Q
    gemm1024<<<gemm_grid, 256, 0, stream>>>(X, Wc + (size_t)D_DIM * D_DIM, bc + D_DIM, Kb);     // K
    scores_k<<<B_ROWS / 4, 256, 0, stream>>>(Qb, Kb, wts);
    gemm1024<<<gemm_grid, 256, 0, stream>>>(X, Wc + (size_t)2 * D_DIM * D_DIM, bc + 2 * D_DIM, Qb); // V (reuse Qb)
    combine_k<<<(B_ROWS * D_DIM / 4) / 256, 256, 0, stream>>>(Qb, wts, out);
}

// Round 4
// 315.731 us; speedup vs baseline: 1.1899x; 1.1899x over previous
//
#include <hip/hip_runtime.h>
#include <hip/hip_bf16.h>
#include <stdint.h>

typedef unsigned short u16;
typedef __bf16 bf16x8 __attribute__((ext_vector_type(8)));
typedef float f32x4 __attribute__((ext_vector_type(4)));

#define D_DIM 1024
#define B_ROWS 16384
#define M_ROWS 32768          // 2*B
#define BM 128
#define BN 128
#define BK 32

// ---------- bf16 bit helpers ----------
__device__ __forceinline__ u16 f2bs(float f) {
    union { float f; unsigned u; } v; v.f = f;
    unsigned r = v.u + 0x7FFFu + ((v.u >> 16) & 1u);   // RNE
    return (u16)(r >> 16);
}
__device__ __forceinline__ float bs2f(unsigned bits16) {
    union { unsigned u; float f; } v; v.u = bits16 << 16;
    return v.f;
}
__device__ __forceinline__ float bidx(uint2 v, int e) {
    unsigned w = (e < 2) ? v.x : v.y;
    unsigned sh = (unsigned)(e & 1) * 16u;
    return bs2f((w >> sh) & 0xFFFFu);
}
__device__ __forceinline__ uint2 pack4(float4 f) {
    uint2 r;
    r.x = (unsigned)f2bs(f.x) | ((unsigned)f2bs(f.y) << 16);
    r.y = (unsigned)f2bs(f.z) | ((unsigned)f2bs(f.w) << 16);
    return r;
}

#define GLD16(gsrc, ldst)                                                      \
    __builtin_amdgcn_global_load_lds(                                          \
        (const __attribute__((address_space(1))) void*)(gsrc),                 \
        (__attribute__((address_space(3))) void*)(ldst), 16, 0, 0)

// ---------- feats fp32 -> bf16, interleaved rows (2b, 2b+1) ----------
__global__ __launch_bounds__(256) void cvt_feats(const float* __restrict__ f1,
                                                 const float* __restrict__ f2,
                                                 u16* __restrict__ X) {
    size_t i4   = (size_t)blockIdx.x * 256 + threadIdx.x;
    size_t base = i4 * 4;
    size_t brow = base >> 10;
    size_t col  = base & 1023;
    float4 a = *(const float4*)(f1 + base);
    float4 b = *(const float4*)(f2 + base);
    *(uint2*)(X + (2 * brow) * D_DIM + col)     = pack4(a);
    *(uint2*)(X + (2 * brow + 1) * D_DIM + col) = pack4(b);
}

// ---------- Wv fp32 -> bf16 straight copy ----------
__global__ __launch_bounds__(256) void cvt_wv(const float* __restrict__ Wv,
                                              u16* __restrict__ Wvb) {
    size_t base = ((size_t)blockIdx.x * 256 + threadIdx.x) * 4;
    *(uint2*)(Wvb + base) = pack4(*(const float4*)(Wv + base));
}

// ---------- 1024x1024 fp32 -> bf16 TRANSPOSED (out[c][r] = in[r][c]) ----------
__global__ __launch_bounds__(256) void transpose_bf16(const float* __restrict__ in,
                                                      u16* __restrict__ out) {
    __shared__ float lds[32][33];
    const int tx = threadIdx.x & 31;
    const int ty = threadIdx.x >> 5;           // 0..7
    const int r0 = (blockIdx.x >> 5) * 32;
    const int c0 = (blockIdx.x & 31) * 32;
#pragma unroll
    for (int i = 0; i < 4; ++i) {
        int r = ty + i * 8;
        lds[r][tx] = in[(size_t)(r0 + r) * D_DIM + c0 + tx];
    }
    __syncthreads();
#pragma unroll
    for (int i = 0; i < 4; ++i) {
        int r = ty + i * 8;
        out[(size_t)(c0 + r) * D_DIM + r0 + tx] = f2bs(lds[tx][r]);
    }
}

// ---------- u = Wq^T bk, v = Wk^T bq, c = bq.bk ----------
__global__ __launch_bounds__(256) void uvc_k(const float* __restrict__ Wq,
                                             const float* __restrict__ Wk,
                                             const float* __restrict__ bq,
                                             const float* __restrict__ bk,
                                             float* __restrict__ u,
                                             float* __restrict__ v,
                                             float* __restrict__ cbuf) {
    const int d = blockIdx.x * 256 + threadIdx.x;
    float au = 0.f, av = 0.f;
    for (int f = 0; f < D_DIM; ++f) {
        au = fmaf(Wq[(size_t)f * D_DIM + d], bk[f], au);
        av = fmaf(Wk[(size_t)f * D_DIM + d], bq[f], av);
    }
    u[d] = au;
    v[d] = av;
    if (blockIdx.x == 0) {
        __shared__ float red[256];
        float p = 0.f;
        for (int f = threadIdx.x; f < D_DIM; f += 256) p = fmaf(bq[f], bk[f], p);
        red[threadIdx.x] = p;
        __syncthreads();
        for (int s = 128; s; s >>= 1) {
            if (threadIdx.x < s) red[threadIdx.x] += red[threadIdx.x + s];
            __syncthreads();
        }
        if (threadIdx.x == 0) cbuf[0] = red[0];
    }
}

// ---------- generic C[r,c] = sum_k A[r,k]*W[c,k] (+bias), bf16 out ----------
__global__ __launch_bounds__(256) void gemm_bt(const u16* __restrict__ A,
                                               const u16* __restrict__ W,
                                               const float* __restrict__ bias,
                                               u16* __restrict__ C, int ncols) {
    constexpr int K = D_DIM;
    __shared__ u16 As[BM * BK];
    __shared__ u16 Bs[BN * BK];

    // XCD-aware swizzle (grid % 8 == 0): each XCD gets a contiguous chunk
    const int cpx  = gridDim.x >> 3;
    const int orig = (blockIdx.x & 7) * cpx + (blockIdx.x >> 3);
    const int nTn = ncols / BN;
    const int m0 = (orig / nTn) * BM, n0 = (orig % nTn) * BN;

    const int tid  = threadIdx.x;
    const int lane = tid & 63;
    const int wave = tid >> 6;
    const int wr = wave >> 1, wc = wave & 1;

    const int lr = lane & 15;
    const int lk = (lane >> 4) * 8;

    f32x4 acc[4][4] = {};

    const int r0 = tid >> 2;
    const int c0 = (tid & 3) * 8;
    const u16* aSrc0 = A + (size_t)(m0 + r0) * K + c0;
    const u16* aSrc1 = A + (size_t)(m0 + 64 + r0) * K + c0;
    const u16* bSrc0 = W + (size_t)(n0 + r0) * K + c0;
    const u16* bSrc1 = W + (size_t)(n0 + 64 + r0) * K + c0;
    u16* aDst0 = As + (size_t)tid * 8;
    u16* aDst1 = As + 2048 + (size_t)tid * 8;
    u16* bDst0 = Bs + (size_t)tid * 8;
    u16* bDst1 = Bs + 2048 + (size_t)tid * 8;

    for (int kt = 0; kt < K; kt += BK) {
        GLD16(aSrc0 + kt, aDst0);
        GLD16(aSrc1 + kt, aDst1);
        GLD16(bSrc0 + kt, bDst0);
        GLD16(bSrc1 + kt, bDst1);
        __syncthreads();

        bf16x8 af[4], bfr[4];
#pragma unroll
        for (int mf = 0; mf < 4; ++mf)
            af[mf] = *(const bf16x8*)(As + (wr * 64 + mf * 16 + lr) * BK + lk);
#pragma unroll
        for (int nf = 0; nf < 4; ++nf)
            bfr[nf] = *(const bf16x8*)(Bs + (wc * 64 + nf * 16 + lr) * BK + lk);
#pragma unroll
        for (int mf = 0; mf < 4; ++mf)
#pragma unroll
            for (int nf = 0; nf < 4; ++nf)
                acc[mf][nf] = __builtin_amdgcn_mfma_f32_16x16x32_bf16(
                    af[mf], bfr[nf], acc[mf][nf], 0, 0, 0);
        __syncthreads();
    }

    const int cr = (lane >> 4) * 4;
    const int cc = lane & 15;
#pragma unroll
    for (int mf = 0; mf < 4; ++mf) {
#pragma unroll
        for (int nf = 0; nf < 4; ++nf) {
            int col = n0 + wc * 64 + nf * 16 + cc;
            float bsv = bias ? bias[col] : 0.f;
#pragma unroll
            for (int j = 0; j < 4; ++j) {
                int row = m0 + wr * 64 + mf * 16 + cr + j;
                C[(size_t)row * ncols + col] = f2bs(acc[mf][nf][j] + bsv);
            }
        }
    }
}

// ---------- scores: s_st = (x_s.G_t + u.x_s + v.x_t + c)/32 -> softmax -> wts ----------
__global__ __launch_bounds__(256) void scores2(const u16* __restrict__ X,
                                               const u16* __restrict__ G,
                                               const float* __restrict__ u,
                                               const float* __restrict__ v,
                                               const float* __restrict__ cbuf,
                                               float2* __restrict__ wts) {
    const int wave = threadIdx.x >> 6;
    const int lane = threadIdx.x & 63;
    const size_t b = (size_t)blockIdx.x * 4 + wave;
    const u16* x0p = X + (2 * b) * D_DIM;
    const u16* x1p = x0p + D_DIM;
    const u16* g0p = G + (2 * b) * D_DIM;
    const u16* g1p = g0p + D_DIM;

    float d00 = 0.f, d01 = 0.f, d10 = 0.f, d11 = 0.f;
    float au0 = 0.f, au1 = 0.f, bv0 = 0.f, bv1 = 0.f;
#pragma unroll
    for (int s = 0; s < 4; ++s) {
        int c = s * 256 + lane * 4;
        uint2 x0 = *(const uint2*)(x0p + c);
        uint2 x1 = *(const uint2*)(x1p + c);
        uint2 g0 = *(const uint2*)(g0p + c);
        uint2 g1 = *(const uint2*)(g1p + c);
        float4 uu = *(const float4*)(u + c);
        float4 vv = *(const float4*)(v + c);
        float uA[4] = {uu.x, uu.y, uu.z, uu.w};
        float vA[4] = {vv.x, vv.y, vv.z, vv.w};
#pragma unroll
        for (int e = 0; e < 4; ++e) {
            float a0 = bidx(x0, e), a1 = bidx(x1, e);
            float c0 = bidx(g0, e), c1 = bidx(g1, e);
            d00 = fmaf(a0, c0, d00); d01 = fmaf(a0, c1, d01);
            d10 = fmaf(a1, c0, d10); d11 = fmaf(a1, c1, d11);
            au0 = fmaf(uA[e], a0, au0); au1 = fmaf(uA[e], a1, au1);
            bv0 = fmaf(vA[e], a0, bv0); bv1 = fmaf(vA[e], a1, bv1);
        }
    }
#pragma unroll
    for (int off = 32; off; off >>= 1) {
        d00 += __shfl_xor(d00, off); d01 += __shfl_xor(d01, off);
        d10 += __shfl_xor(d10, off); d11 += __shfl_xor(d11, off);
        au0 += __shfl_xor(au0, off); au1 += __shfl_xor(au1, off);
        bv0 += __shfl_xor(bv0, off); bv1 += __shfl_xor(bv1, off);
    }
    if (lane == 0) {
        const float cc0 = cbuf[0];
        const float sc = 1.0f / 32.0f;
        float s00 = (d00 + au0 + bv0 + cc0) * sc;
        float s01 = (d01 + au0 + bv1 + cc0) * sc;
        float s10 = (d10 + au1 + bv0 + cc0) * sc;
        float s11 = (d11 + au1 + bv1 + cc0) * sc;
        float mA = fmaxf(s00, s01);
        float e00 = expf(s00 - mA), e01 = expf(s01 - mA);
        float rA = 1.0f / (e00 + e01);
        float mB = fmaxf(s10, s11);
        float e10 = expf(s10 - mB), e11 = expf(s11 - mB);
        float rB = 1.0f / (e10 + e11);
        float2 w;
        w.x = e00 * rA + e10 * rB;
        w.y = e01 * rA + e11 * rB;
        wts[b] = w;
    }
}

// ---------- V-GEMM with fused combine: out[b] = w.x*V[2b] + w.y*V[2b+1] ----------
__global__ __launch_bounds__(256) void gemm_cmb(const u16* __restrict__ A,
                                                const u16* __restrict__ W,
                                                const float* __restrict__ bias,
                                                const float2* __restrict__ wts,
                                                float* __restrict__ out) {
    constexpr int K = D_DIM;
    constexpr int ncols = D_DIM;
    __shared__ u16 As[BM * BK];
    __shared__ u16 Bs[BN * BK];

    const int cpx  = gridDim.x >> 3;
    const int orig = (blockIdx.x & 7) * cpx + (blockIdx.x >> 3);
    const int nTn = ncols / BN;   // 8
    const int m0 = (orig / nTn) * BM, n0 = (orig % nTn) * BN;

    const int tid  = threadIdx.x;
    const int lane = tid & 63;
    const int wave = tid >> 6;
    const int wr = wave >> 1, wc = wave & 1;

    const int lr = lane & 15;
    const int lk = (lane >> 4) * 8;

    f32x4 acc[4][4] = {};

    const int r0 = tid >> 2;
    const int c0 = (tid & 3) * 8;
    const u16* aSrc0 = A + (size_t)(m0 + r0) * K + c0;
    const u16* aSrc1 = A + (size_t)(m0 + 64 + r0) * K + c0;
    const u16* bSrc0 = W + (size_t)(n0 + r0) * K + c0;
    const u16* bSrc1 = W + (size_t)(n0 + 64 + r0) * K + c0;
    u16* aDst0 = As + (size_t)tid * 8;
    u16* aDst1 = As + 2048 + (size_t)tid * 8;
    u16* bDst0 = Bs + (size_t)tid * 8;
    u16* bDst1 = Bs + 2048 + (size_t)tid * 8;

    for (int kt = 0; kt < K; kt += BK) {
        GLD16(aSrc0 + kt, aDst0);
        GLD16(aSrc1 + kt, aDst1);
        GLD16(bSrc0 + kt, bDst0);
        GLD16(bSrc1 + kt, bDst1);
        __syncthreads();

        bf16x8 af[4], bfr[4];
#pragma unroll
        for (int mf = 0; mf < 4; ++mf)
            af[mf] = *(const bf16x8*)(As + (wr * 64 + mf * 16 + lr) * BK + lk);
#pragma unroll
        for (int nf = 0; nf < 4; ++nf)
            bfr[nf] = *(const bf16x8*)(Bs + (wc * 64 + nf * 16 + lr) * BK + lk);
#pragma unroll
        for (int mf = 0; mf < 4; ++mf)
#pragma unroll
            for (int nf = 0; nf < 4; ++nf)
                acc[mf][nf] = __builtin_amdgcn_mfma_f32_16x16x32_bf16(
                    af[mf], bfr[nf], acc[mf][nf], 0, 0, 0);
        __syncthreads();
    }

    // fused epilogue: rows (2p, 2p+1) are j=(0,1) and j=(2,3) of the same lane
    const int cr = (lane >> 4) * 4;
    const int cc = lane & 15;
#pragma unroll
    for (int mf = 0; mf < 4; ++mf) {
        const int rowbase = m0 + wr * 64 + mf * 16 + cr;   // even
        const int p0 = rowbase >> 1;
        const float2 w0 = wts[p0];
        const float2 w1 = wts[p0 + 1];
#pragma unroll
        for (int nf = 0; nf < 4; ++nf) {
            int col = n0 + wc * 64 + nf * 16 + cc;
            float bsv = bias[col];
            float o0 = w0.x * (acc[mf][nf][0] + bsv) + w0.y * (acc[mf][nf][1] + bsv);
            float o1 = w1.x * (acc[mf][nf][2] + bsv) + w1.y * (acc[mf][nf][3] + bsv);
            out[(size_t)p0 * D_DIM + col]       = o0;
            out[(size_t)(p0 + 1) * D_DIM + col] = o1;
        }
    }
}

extern "C" void kernel_launch(void* const* d_in, const int* in_sizes, int n_in,
                              void* d_out, int out_size, void* d_ws, size_t ws_size,
                              hipStream_t stream) {
    const float* f1 = (const float*)d_in[0];
    const float* f2 = (const float*)d_in[1];
    const float* Wq = (const float*)d_in[2];
    const float* bq = (const float*)d_in[3];
    const float* Wk = (const float*)d_in[4];
    const float* bk = (const float*)d_in[5];
    const float* Wv = (const float*)d_in[6];
    const float* bv = (const float*)d_in[7];
    float* out = (float*)d_out;

    // workspace layout (~138 MB)
    char*   w    = (char*)d_ws;
    u16*    X    = (u16*)w;                                  // [32768,1024] bf16 (64 MB)
    u16*    G    = X + (size_t)M_ROWS * D_DIM;               // [32768,1024] bf16 (64 MB)
    u16*    Wvb  = G + (size_t)M_ROWS * D_DIM;               // [1024,1024] bf16 (2 MB)
    u16*    WqT  = Wvb + (size_t)D_DIM * D_DIM;              // [1024,1024] bf16 (2 MB)
    u16*    WkT  = WqT + (size_t)D_DIM * D_DIM;              // [1024,1024] bf16 (2 MB)
    u16*    Mb   = WkT + (size_t)D_DIM * D_DIM;              // [1024,1024] bf16 (2 MB)
    float*  u    = (float*)(Mb + (size_t)D_DIM * D_DIM);     // [1024] f32
    float*  v    = u + D_DIM;                                // [1024] f32
    float*  cbuf = v + D_DIM;                                // [64] f32
    float2* wts  = (float2*)(cbuf + 64);                     // [16384] f32x2 (128 KB)

    cvt_feats<<<(B_ROWS * D_DIM / 4) / 256, 256, 0, stream>>>(f1, f2, X);
    cvt_wv<<<(D_DIM * D_DIM / 4) / 256, 256, 0, stream>>>(Wv, Wvb);
    transpose_bf16<<<1024, 256, 0, stream>>>(Wq, WqT);
    transpose_bf16<<<1024, 256, 0, stream>>>(Wk, WkT);
    uvc_k<<<D_DIM / 256, 256, 0, stream>>>(Wq, Wk, bq, bk, u, v, cbuf);

    // M = Wq^T @ Wk  : [1024,1024]
    gemm_bt<<<(D_DIM / BM) * (D_DIM / BN), 256, 0, stream>>>(WqT, WkT, nullptr, Mb, D_DIM);
    // G = X @ M^T    : [32768,1024]
    gemm_bt<<<(M_ROWS / BM) * (D_DIM / BN), 256, 0, stream>>>(X, Mb, nullptr, G, D_DIM);
    // per-pair scores -> combine weights
    scores2<<<B_ROWS / 4, 256, 0, stream>>>(X, G, u, v, cbuf, wts);
    // V GEMM + fused combine -> out
    gemm_cmb<<<(M_ROWS / BM) * (D_DIM / BN), 256, 0, stream>>>(X, Wvb, bv, wts, out);
}

// Round 5
// 234.506 us; speedup vs baseline: 1.6021x; 1.3464x over previous
//
#include <hip/hip_runtime.h>
#include <hip/hip_bf16.h>
#include <stdint.h>

typedef unsigned short u16;
typedef __bf16 bf16x8 __attribute__((ext_vector_type(8)));
typedef float f32x4 __attribute__((ext_vector_type(4)));

#define D_DIM 1024
#define B_ROWS 16384
#define M_ROWS 32768          // 2*B
#define BM 128
#define BN 128
#define BK 64

// ---------- bf16 bit helpers ----------
__device__ __forceinline__ u16 f2bs(float f) {
    union { float f; unsigned u; } v; v.f = f;
    unsigned r = v.u + 0x7FFFu + ((v.u >> 16) & 1u);   // RNE
    return (u16)(r >> 16);
}
__device__ __forceinline__ float bs2f(unsigned bits16) {
    union { unsigned u; float f; } v; v.u = bits16 << 16;
    return v.f;
}
__device__ __forceinline__ float bidx(uint2 v, int e) {
    unsigned w = (e < 2) ? v.x : v.y;
    unsigned sh = (unsigned)(e & 1) * 16u;
    return bs2f((w >> sh) & 0xFFFFu);
}
__device__ __forceinline__ uint2 pack4(float4 f) {
    uint2 r;
    r.x = (unsigned)f2bs(f.x) | ((unsigned)f2bs(f.y) << 16);
    r.y = (unsigned)f2bs(f.z) | ((unsigned)f2bs(f.w) << 16);
    return r;
}

#define GLD16(gsrc, ldst)                                                      \
    __builtin_amdgcn_global_load_lds(                                          \
        (const __attribute__((address_space(1))) void*)(gsrc),                 \
        (__attribute__((address_space(3))) void*)(ldst), 16, 0, 0)

// ---------- feats fp32 -> bf16, interleaved rows (2b, 2b+1) ----------
__global__ __launch_bounds__(256) void cvt_feats(const float* __restrict__ f1,
                                                 const float* __restrict__ f2,
                                                 u16* __restrict__ X) {
    size_t i4   = (size_t)blockIdx.x * 256 + threadIdx.x;
    size_t base = i4 * 4;
    size_t brow = base >> 10;
    size_t col  = base & 1023;
    float4 a = *(const float4*)(f1 + base);
    float4 b = *(const float4*)(f2 + base);
    *(uint2*)(X + (2 * brow) * D_DIM + col)     = pack4(a);
    *(uint2*)(X + (2 * brow + 1) * D_DIM + col) = pack4(b);
}

// ---------- Wv fp32 -> bf16 straight copy ----------
__global__ __launch_bounds__(256) void cvt_wv(const float* __restrict__ Wv,
                                              u16* __restrict__ Wvb) {
    size_t base = ((size_t)blockIdx.x * 256 + threadIdx.x) * 4;
    *(uint2*)(Wvb + base) = pack4(*(const float4*)(Wv + base));
}

// ---------- 1024x1024 fp32 -> bf16 TRANSPOSED (out[c][r] = in[r][c]) ----------
__global__ __launch_bounds__(256) void transpose_bf16(const float* __restrict__ in,
                                                      u16* __restrict__ out) {
    __shared__ float lds[32][33];
    const int tx = threadIdx.x & 31;
    const int ty = threadIdx.x >> 5;           // 0..7
    const int r0 = (blockIdx.x >> 5) * 32;
    const int c0 = (blockIdx.x & 31) * 32;
#pragma unroll
    for (int i = 0; i < 4; ++i) {
        int r = ty + i * 8;
        lds[r][tx] = in[(size_t)(r0 + r) * D_DIM + c0 + tx];
    }
    __syncthreads();
#pragma unroll
    for (int i = 0; i < 4; ++i) {
        int r = ty + i * 8;
        out[(size_t)(c0 + r) * D_DIM + r0 + tx] = f2bs(lds[tx][r]);
    }
}

// ---------- u = Wq^T bk, v = Wk^T bq, c = bq.bk (parallel over f-chunks) ----------
__global__ __launch_bounds__(256) void uvc_k(const float* __restrict__ Wq,
                                             const float* __restrict__ Wk,
                                             const float* __restrict__ bq,
                                             const float* __restrict__ bk,
                                             float* __restrict__ u,
                                             float* __restrict__ v,
                                             float* __restrict__ cbuf) {
    const int dl = threadIdx.x & 31;           // d-lane within block
    const int fg = threadIdx.x >> 5;           // f-group 0..7
    const int d  = blockIdx.x * 32 + dl;
    float au = 0.f, av = 0.f;
    const int f0 = fg * 128;
    for (int f = f0; f < f0 + 128; ++f) {
        au = fmaf(Wq[(size_t)f * D_DIM + d], bk[f], au);
        av = fmaf(Wk[(size_t)f * D_DIM + d], bq[f], av);
    }
    __shared__ float su[8][32], sv[8][32];
    su[fg][dl] = au; sv[fg][dl] = av;
    __syncthreads();
    if (fg == 0) {
        float a = 0.f, b2 = 0.f;
#pragma unroll
        for (int g = 0; g < 8; ++g) { a += su[g][dl]; b2 += sv[g][dl]; }
        u[d] = a; v[d] = b2;
    }
    if (blockIdx.x == 0) {
        __shared__ float red[256];
        float p = 0.f;
        for (int f = threadIdx.x; f < D_DIM; f += 256) p = fmaf(bq[f], bk[f], p);
        red[threadIdx.x] = p;
        __syncthreads();
        for (int s = 128; s; s >>= 1) {
            if (threadIdx.x < s) red[threadIdx.x] += red[threadIdx.x + s];
            __syncthreads();
        }
        if (threadIdx.x == 0) cbuf[0] = red[0];
    }
}

// ============================================================================
// GEMM core, BK=64, XOR-swizzled LDS (rule #21: linear gld_lds dst +
// involution on SOURCE col + same XOR on ds_read).
// Logical LDS unit (R, c) [c = 16B col 0..7] lives at physical col c^(R&7).
// ============================================================================
// ---------- generic C[r,c] = sum_k A[r,k]*W[c,k] (+bias), bf16 out ----------
__global__ __launch_bounds__(256, 3) void gemm_bt(const u16* __restrict__ A,
                                                  const u16* __restrict__ W,
                                                  const float* __restrict__ bias,
                                                  u16* __restrict__ C, int ncols) {
    constexpr int K = D_DIM;
    __shared__ u16 As[BM * BK];   // 16 KB
    __shared__ u16 Bs[BN * BK];   // 16 KB

    // XCD-aware swizzle (grid % 8 == 0)
    const int cpx  = gridDim.x >> 3;
    const int orig = (blockIdx.x & 7) * cpx + (blockIdx.x >> 3);
    const int nTn = ncols / BN;
    const int m0 = (orig / nTn) * BM, n0 = (orig % nTn) * BN;

    const int tid  = threadIdx.x;
    const int lane = tid & 63;
    const int wave = tid >> 6;
    const int wr = wave >> 1, wc = wave & 1;    // 2x2 waves -> 64x64 each

    const int lr = lane & 15;
    const int kg = lane >> 4;                   // 0..3

    f32x4 acc[4][4] = {};

    // staging: round i covers rows i*32..i*32+31; thread -> (row, swz col)
    const int sr  = tid >> 3;                               // row-in-round 0..31
    const int scs = ((tid & 7) ^ ((tid >> 3) & 7)) * 8;     // swizzled src col (elems)
    const u16* aRow = A + (size_t)(m0 + sr) * K + scs;
    const u16* bRow = W + (size_t)(n0 + sr) * K + scs;
    u16* aDst = As + tid * 8;
    u16* bDst = Bs + tid * 8;

    for (int kt = 0; kt < K; kt += BK) {
#pragma unroll
        for (int i = 0; i < 4; ++i) {
            GLD16(aRow + (size_t)i * 32 * K + kt, aDst + i * 2048);
            GLD16(bRow + (size_t)i * 32 * K + kt, bDst + i * 2048);
        }
        __syncthreads();   // compiler emits vmcnt(0) drain before barrier

#pragma unroll
        for (int kk = 0; kk < 2; ++kk) {
            bf16x8 af[4], bfr[4];
            const int kx = kk * 4 + kg;
#pragma unroll
            for (int mf = 0; mf < 4; ++mf) {
                const int R = wr * 64 + mf * 16 + lr;
                af[mf] = *(const bf16x8*)(As + R * 64 + ((kx ^ (R & 7)) * 8));
            }
#pragma unroll
            for (int nf = 0; nf < 4; ++nf) {
                const int S = wc * 64 + nf * 16 + lr;
                bfr[nf] = *(const bf16x8*)(Bs + S * 64 + ((kx ^ (S & 7)) * 8));
            }
#pragma unroll
            for (int mf = 0; mf < 4; ++mf)
#pragma unroll
                for (int nf = 0; nf < 4; ++nf)
                    acc[mf][nf] = __builtin_amdgcn_mfma_f32_16x16x32_bf16(
                        af[mf], bfr[nf], acc[mf][nf], 0, 0, 0);
        }
        __syncthreads();
    }

    // epilogue: C/D layout col=lane&15, row=(lane>>4)*4+j  [verified m89]
    const int cr = (lane >> 4) * 4;
    const int cc = lane & 15;
#pragma unroll
    for (int mf = 0; mf < 4; ++mf) {
#pragma unroll
        for (int nf = 0; nf < 4; ++nf) {
            int col = n0 + wc * 64 + nf * 16 + cc;
            float bsv = bias ? bias[col] : 0.f;
#pragma unroll
            for (int j = 0; j < 4; ++j) {
                int row = m0 + wr * 64 + mf * 16 + cr + j;
                C[(size_t)row * ncols + col] = f2bs(acc[mf][nf][j] + bsv);
            }
        }
    }
}

// ---------- V-GEMM with fused combine: out[b] = w.x*V[2b] + w.y*V[2b+1] ----------
__global__ __launch_bounds__(256, 3) void gemm_cmb(const u16* __restrict__ A,
                                                   const u16* __restrict__ W,
                                                   const float* __restrict__ bias,
                                                   const float2* __restrict__ wts,
                                                   float* __restrict__ out) {
    constexpr int K = D_DIM;
    constexpr int ncols = D_DIM;
    __shared__ u16 As[BM * BK];
    __shared__ u16 Bs[BN * BK];

    const int cpx  = gridDim.x >> 3;
    const int orig = (blockIdx.x & 7) * cpx + (blockIdx.x >> 3);
    const int nTn = ncols / BN;   // 8
    const int m0 = (orig / nTn) * BM, n0 = (orig % nTn) * BN;

    const int tid  = threadIdx.x;
    const int lane = tid & 63;
    const int wave = tid >> 6;
    const int wr = wave >> 1, wc = wave & 1;

    const int lr = lane & 15;
    const int kg = lane >> 4;

    f32x4 acc[4][4] = {};

    const int sr  = tid >> 3;
    const int scs = ((tid & 7) ^ ((tid >> 3) & 7)) * 8;
    const u16* aRow = A + (size_t)(m0 + sr) * K + scs;
    const u16* bRow = W + (size_t)(n0 + sr) * K + scs;
    u16* aDst = As + tid * 8;
    u16* bDst = Bs + tid * 8;

    for (int kt = 0; kt < K; kt += BK) {
#pragma unroll
        for (int i = 0; i < 4; ++i) {
            GLD16(aRow + (size_t)i * 32 * K + kt, aDst + i * 2048);
            GLD16(bRow + (size_t)i * 32 * K + kt, bDst + i * 2048);
        }
        __syncthreads();

#pragma unroll
        for (int kk = 0; kk < 2; ++kk) {
            bf16x8 af[4], bfr[4];
            const int kx = kk * 4 + kg;
#pragma unroll
            for (int mf = 0; mf < 4; ++mf) {
                const int R = wr * 64 + mf * 16 + lr;
                af[mf] = *(const bf16x8*)(As + R * 64 + ((kx ^ (R & 7)) * 8));
            }
#pragma unroll
            for (int nf = 0; nf < 4; ++nf) {
                const int S = wc * 64 + nf * 16 + lr;
                bfr[nf] = *(const bf16x8*)(Bs + S * 64 + ((kx ^ (S & 7)) * 8));
            }
#pragma unroll
            for (int mf = 0; mf < 4; ++mf)
#pragma unroll
                for (int nf = 0; nf < 4; ++nf)
                    acc[mf][nf] = __builtin_amdgcn_mfma_f32_16x16x32_bf16(
                        af[mf], bfr[nf], acc[mf][nf], 0, 0, 0);
        }
        __syncthreads();
    }

    // fused epilogue: rows (2p, 2p+1) are j=(0,1) and j=(2,3) of the same lane
    const int cr = (lane >> 4) * 4;
    const int cc = lane & 15;
#pragma unroll
    for (int mf = 0; mf < 4; ++mf) {
        const int rowbase = m0 + wr * 64 + mf * 16 + cr;   // even
        const int p0 = rowbase >> 1;
        const float2 w0 = wts[p0];
        const float2 w1 = wts[p0 + 1];
#pragma unroll
        for (int nf = 0; nf < 4; ++nf) {
            int col = n0 + wc * 64 + nf * 16 + cc;
            float bsv = bias[col];
            float o0 = w0.x * (acc[mf][nf][0] + bsv) + w0.y * (acc[mf][nf][1] + bsv);
            float o1 = w1.x * (acc[mf][nf][2] + bsv) + w1.y * (acc[mf][nf][3] + bsv);
            out[(size_t)p0 * D_DIM + col]       = o0;
            out[(size_t)(p0 + 1) * D_DIM + col] = o1;
        }
    }
}

// ---------- scores: s_st = (x_s.G_t + u.x_s + v.x_t + c)/32 -> softmax -> wts ----------
__global__ __launch_bounds__(256) void scores2(const u16* __restrict__ X,
                                               const u16* __restrict__ G,
                                               const float* __restrict__ u,
                                               const float* __restrict__ v,
                                               const float* __restrict__ cbuf,
                                               float2* __restrict__ wts) {
    const int wave = threadIdx.x >> 6;
    const int lane = threadIdx.x & 63;
    const size_t b = (size_t)blockIdx.x * 4 + wave;
    const u16* x0p = X + (2 * b) * D_DIM;
    const u16* x1p = x0p + D_DIM;
    const u16* g0p = G + (2 * b) * D_DIM;
    const u16* g1p = g0p + D_DIM;

    float d00 = 0.f, d01 = 0.f, d10 = 0.f, d11 = 0.f;
    float au0 = 0.f, au1 = 0.f, bv0 = 0.f, bv1 = 0.f;
#pragma unroll
    for (int s = 0; s < 4; ++s) {
        int c = s * 256 + lane * 4;
        uint2 x0 = *(const uint2*)(x0p + c);
        uint2 x1 = *(const uint2*)(x1p + c);
        uint2 g0 = *(const uint2*)(g0p + c);
        uint2 g1 = *(const uint2*)(g1p + c);
        float4 uu = *(const float4*)(u + c);
        float4 vv = *(const float4*)(v + c);
        float uA[4] = {uu.x, uu.y, uu.z, uu.w};
        float vA[4] = {vv.x, vv.y, vv.z, vv.w};
#pragma unroll
        for (int e = 0; e < 4; ++e) {
            float a0 = bidx(x0, e), a1 = bidx(x1, e);
            float c0 = bidx(g0, e), c1 = bidx(g1, e);
            d00 = fmaf(a0, c0, d00); d01 = fmaf(a0, c1, d01);
            d10 = fmaf(a1, c0, d10); d11 = fmaf(a1, c1, d11);
            au0 = fmaf(uA[e], a0, au0); au1 = fmaf(uA[e], a1, au1);
            bv0 = fmaf(vA[e], a0, bv0); bv1 = fmaf(vA[e], a1, bv1);
        }
    }
#pragma unroll
    for (int off = 32; off; off >>= 1) {
        d00 += __shfl_xor(d00, off); d01 += __shfl_xor(d01, off);
        d10 += __shfl_xor(d10, off); d11 += __shfl_xor(d11, off);
        au0 += __shfl_xor(au0, off); au1 += __shfl_xor(au1, off);
        bv0 += __shfl_xor(bv0, off); bv1 += __shfl_xor(bv1, off);
    }
    if (lane == 0) {
        const float cc0 = cbuf[0];
        const float sc = 1.0f / 32.0f;
        float s00 = (d00 + au0 + bv0 + cc0) * sc;
        float s01 = (d01 + au0 + bv1 + cc0) * sc;
        float s10 = (d10 + au1 + bv0 + cc0) * sc;
        float s11 = (d11 + au1 + bv1 + cc0) * sc;
        float mA = fmaxf(s00, s01);
        float e00 = expf(s00 - mA), e01 = expf(s01 - mA);
        float rA = 1.0f / (e00 + e01);
        float mB = fmaxf(s10, s11);
        float e10 = expf(s10 - mB), e11 = expf(s11 - mB);
        float rB = 1.0f / (e10 + e11);
        float2 w;
        w.x = e00 * rA + e10 * rB;
        w.y = e01 * rA + e11 * rB;
        wts[b] = w;
    }
}

extern "C" void kernel_launch(void* const* d_in, const int* in_sizes, int n_in,
                              void* d_out, int out_size, void* d_ws, size_t ws_size,
                              hipStream_t stream) {
    const float* f1 = (const float*)d_in[0];
    const float* f2 = (const float*)d_in[1];
    const float* Wq = (const float*)d_in[2];
    const float* bq = (const float*)d_in[3];
    const float* Wk = (const float*)d_in[4];
    const float* bk = (const float*)d_in[5];
    const float* Wv = (const float*)d_in[6];
    const float* bv = (const float*)d_in[7];
    float* out = (float*)d_out;

    // workspace layout (~138 MB)
    char*   w    = (char*)d_ws;
    u16*    X    = (u16*)w;                                  // [32768,1024] bf16 (64 MB)
    u16*    G    = X + (size_t)M_ROWS * D_DIM;               // [32768,1024] bf16 (64 MB)
    u16*    Wvb  = G + (size_t)M_ROWS * D_DIM;               // [1024,1024] bf16 (2 MB)
    u16*    WqT  = Wvb + (size_t)D_DIM * D_DIM;              // [1024,1024] bf16 (2 MB)
    u16*    WkT  = WqT + (size_t)D_DIM * D_DIM;              // [1024,1024] bf16 (2 MB)
    u16*    Mb   = WkT + (size_t)D_DIM * D_DIM;              // [1024,1024] bf16 (2 MB)
    float*  u    = (float*)(Mb + (size_t)D_DIM * D_DIM);     // [1024] f32
    float*  v    = u + D_DIM;                                // [1024] f32
    float*  cbuf = v + D_DIM;                                // [64] f32
    float2* wts  = (float2*)(cbuf + 64);                     // [16384] f32x2 (128 KB)

    cvt_feats<<<(B_ROWS * D_DIM / 4) / 256, 256, 0, stream>>>(f1, f2, X);
    cvt_wv<<<(D_DIM * D_DIM / 4) / 256, 256, 0, stream>>>(Wv, Wvb);
    transpose_bf16<<<1024, 256, 0, stream>>>(Wq, WqT);
    transpose_bf16<<<1024, 256, 0, stream>>>(Wk, WkT);
    uvc_k<<<D_DIM / 32, 256, 0, stream>>>(Wq, Wk, bq, bk, u, v, cbuf);

    // M = Wq^T @ Wk  : [1024,1024]
    gemm_bt<<<(D_DIM / BM) * (D_DIM / BN), 256, 0, stream>>>(WqT, WkT, nullptr, Mb, D_DIM);
    // G = X @ M^T    : [32768,1024]
    gemm_bt<<<(M_ROWS / BM) * (D_DIM / BN), 256, 0, stream>>>(X, Mb, nullptr, G, D_DIM);
    // per-pair scores -> combine weights
    scores2<<<B_ROWS / 4, 256, 0, stream>>>(X, G, u, v, cbuf, wts);
    // V GEMM + fused combine -> out
    gemm_cmb<<<(M_ROWS / BM) * (D_DIM / BN), 256, 0, stream>>>(X, Wvb, bv, wts, out);
}